// Round 8
// baseline (2796.555 us; speedup 1.0000x reference)
//
#include <hip/hip_runtime.h>

// VectorQuantizer: N=16384 rows (16*32*32), C=256, K=8192 codebook.
//   inputs  fp32: d_in[0]=hidden_states (B,C,H,W), d_in[1]=emb_weights (K,C)
//   outputs fp32: z_q (4194304) ++ indices (16384) ++ loss (1)
//
// R7 post-mortem: TM=16 acc spilled (VGPR clamp 128; WRITE_SIZE 977 MB of
// scratch). R8: TM=8xTN=8 (acc=64, no spill) + eb read DIRECT FROM GLOBAL
// (L1 broadcast; es LDS tile deleted) + fa via LDS 16-lane broadcast reads.
// Per-(row,cand) fmaf chain order unchanged -> bit-exact vs r6/r7 (absmax 0).
//
// d = fp32(A_n - 2*M_nk); A_n bit-exact vs numpy pairwise sum; argmin
// tie-break = lowest index via u64 key=(bits(d)<<32)|idx (d>0 always).
//
// WORKSPACE-FREE: scratch aliases the z_q float region of d_out (overwritten
// by the final kZQ pass). No d_ws, no hipMemsetAsync.
//   A       float[16384]  @ float idx [0, 16384)
//   keys    u64[16384]    @ float idx [16384, 49152)
//   lossAcc double        @ float idx [49152, 49154)
// Order: kA -> kGEMM -> kPost -> kLoss -> kZQ.

#define N_ROWS 16384
#define K_CAND 8192
#define CDIM   256
#define NELEM  4194304   // 16*256*32*32

#define SA_FLT 0
#define SK_FLT 16384
#define SL_FLT 49152

// ---- pass 1: A[n] = numpy-pairwise-exact sum of f[n][c]^2; init keys/loss --
__global__ void kA(const float* __restrict__ hs, float* __restrict__ out) {
    float* A = out + SA_FLT;
    unsigned long long* keys = (unsigned long long*)(out + SK_FLT);
    int n = blockIdx.x * 256 + threadIdx.x;
    keys[n] = ~0ull;                      // "+inf" key
    if (n == 0) *(double*)(out + SL_FLT) = 0.0;
    int b = n >> 10, yx = n & 1023;
    const float* base = hs + ((size_t)b << 18) + yx;   // b*256*1024
    float hsum[2];
    for (int h = 0; h < 2; ++h) {
        float r[8];
        #pragma unroll
        for (int j = 0; j < 8; ++j) {
            float x = base[(size_t)(h * 128 + j) << 10];
            r[j] = __fmul_rn(x, x);
        }
        for (int i = 8; i < 128; i += 8) {
            #pragma unroll
            for (int j = 0; j < 8; ++j) {
                float x = base[(size_t)(h * 128 + i + j) << 10];
                r[j] = __fadd_rn(r[j], __fmul_rn(x, x));
            }
        }
        hsum[h] = __fadd_rn(
            __fadd_rn(__fadd_rn(r[0], r[1]), __fadd_rn(r[2], r[3])),
            __fadd_rn(__fadd_rn(r[4], r[5]), __fadd_rn(r[6], r[7])));
    }
    A[n] = __fadd_rn(hsum[0], hsum[1]);
}

// ---- pass 2: distance GEMM + fused argmin ----------------------------------
#define BM 128
#define BN 128
#define BK 32
#define LDK 36      // BK+4: float4-aligned rows
#define TM 8
#define TN 8
#define SPLIT 8
#define CAND_PER (K_CAND / SPLIT)   // 1024

__global__ __launch_bounds__(256, 2) void kGEMM(const float* __restrict__ hs,
                                                const float* __restrict__ emb,
                                                float* __restrict__ out) {
    const float* Arr = out + SA_FLT;
    unsigned long long* keys = (unsigned long long*)(out + SK_FLT);
    __shared__ __align__(16) float fs[BM][LDK];   // 18432 B (only LDS tile)
    const int t  = threadIdx.x;
    const int tx = t & 15, ty = t >> 4;
    const int row0      = (blockIdx.x >> 3) * BM;       // 128 row-blocks
    const int cand_base = (blockIdx.x & 7) * CAND_PER;  // 8 cand splits
    const int b   = row0 >> 10;      // 128 | 1024 so the whole tile shares b
    const int yx0 = row0 & 1023;

    unsigned long long best[TM];
    #pragma unroll
    for (int m = 0; m < TM; ++m) best[m] = ~0ull;

    const int srow = t >> 1;          // fs staging: 2 threads per row
    const int skh  = (t & 1) * 16;    // k-half

    for (int cc = 0; cc < CAND_PER / BN; ++cc) {        // 8
        const int cand0 = cand_base + cc * BN;
        // per-thread emb base for its tx-column of candidates
        const float* embp = emb + ((size_t)(cand0 + tx) << 8);
        float acc[TM][TN];
        #pragma unroll
        for (int m = 0; m < TM; ++m)
            #pragma unroll
            for (int j = 0; j < TN; ++j) acc[m][j] = 0.0f;

        for (int kc = 0; kc < CDIM / BK; ++kc) {        // 8
            __syncthreads();
            // stage f tile: 128 rows x 32 k; 2 threads/row, 16 k each.
            // Global loads coalesced (lane pairs advance yx).
            {
                const float* g = hs + (((size_t)(b * 256 + kc * BK + skh)) << 10)
                                    + (yx0 + srow);
                #pragma unroll
                for (int q = 0; q < 4; ++q) {
                    float4 v;
                    v.x = g[(size_t)(4 * q + 0) << 10];
                    v.y = g[(size_t)(4 * q + 1) << 10];
                    v.z = g[(size_t)(4 * q + 2) << 10];
                    v.w = g[(size_t)(4 * q + 3) << 10];
                    *(float4*)&fs[srow][skh + 4 * q] = v;
                }
            }
            __syncthreads();

            const float* ek = embp + kc * BK;
            #pragma unroll
            for (int k4 = 0; k4 < BK / 4; ++k4) {
                // j-group 0: eb[0..3] from global (L1 broadcast across ty)
                float4 eb[4];
                #pragma unroll
                for (int j = 0; j < 4; ++j)
                    eb[j] = *(const float4*)(ek + ((size_t)(16 * j) << 8) + 4 * k4);
                #pragma unroll
                for (int m = 0; m < TM; ++m) {
                    float4 fa = *(const float4*)&fs[ty + 16 * m][4 * k4];
                    #pragma unroll
                    for (int j = 0; j < 4; ++j) {
                        acc[m][j] = fmaf(fa.x, eb[j].x, acc[m][j]);
                        acc[m][j] = fmaf(fa.y, eb[j].y, acc[m][j]);
                        acc[m][j] = fmaf(fa.z, eb[j].z, acc[m][j]);
                        acc[m][j] = fmaf(fa.w, eb[j].w, acc[m][j]);
                    }
                }
                // j-group 1: eb[4..7]
                #pragma unroll
                for (int j = 0; j < 4; ++j)
                    eb[j] = *(const float4*)(ek + ((size_t)(16 * (j + 4)) << 8) + 4 * k4);
                #pragma unroll
                for (int m = 0; m < TM; ++m) {
                    float4 fa = *(const float4*)&fs[ty + 16 * m][4 * k4];
                    #pragma unroll
                    for (int j = 0; j < 4; ++j) {
                        acc[m][j + 4] = fmaf(fa.x, eb[j].x, acc[m][j + 4]);
                        acc[m][j + 4] = fmaf(fa.y, eb[j].y, acc[m][j + 4]);
                        acc[m][j + 4] = fmaf(fa.z, eb[j].z, acc[m][j + 4]);
                        acc[m][j + 4] = fmaf(fa.w, eb[j].w, acc[m][j + 4]);
                    }
                }
            }
        }
        // chunk epilogue: d = fp32(A - 2*dot), lexicographic (d, idx) min
        #pragma unroll
        for (int m = 0; m < TM; ++m) {
            float Am = Arr[row0 + ty + 16 * m];
            #pragma unroll
            for (int j = 0; j < TN; ++j) {
                float d = __fsub_rn(Am, __fadd_rn(acc[m][j], acc[m][j]));
                unsigned long long key =
                    ((unsigned long long)__float_as_uint(d) << 32)
                    | (unsigned)(cand0 + tx + 16 * j);
                if (key < best[m]) best[m] = key;
            }
        }
    }
    // reduce across the 16 tx lanes (same wave) -> 1 atomic per row per wave
    #pragma unroll
    for (int m = 0; m < TM; ++m) {
        unsigned long long k = best[m];
        #pragma unroll
        for (int off = 1; off < 16; off <<= 1) {
            unsigned long long o = __shfl_xor(k, off, 64);
            if (o < k) k = o;
        }
        if (tx == 0) atomicMin(&keys[row0 + ty + 16 * m], k);
    }
}

// ---- pass 3: keys -> fp32 index output + loss partial sum ------------------
__global__ void kPost(float* __restrict__ out) {
    const unsigned long long* keys = (const unsigned long long*)(out + SK_FLT);
    double* lossAcc = (double*)(out + SL_FLT);
    __shared__ double sd[256];
    int n = blockIdx.x * 256 + threadIdx.x;
    unsigned long long key = keys[n];
    unsigned idx = (unsigned)(key & 0xffffffffu) & 8191u;   // clamp: in-bounds
    float d = __uint_as_float((unsigned)(key >> 32));
    out[NELEM + n] = (float)idx;            // fp32 index output (exact)
    sd[threadIdx.x] = (double)d;
    __syncthreads();
    for (int s = 128; s > 0; s >>= 1) {
        if (threadIdx.x < s) sd[threadIdx.x] += sd[threadIdx.x + s];
        __syncthreads();
    }
    if (threadIdx.x == 0) atomicAdd(lossAcc, sd[0]);
}

// ---- pass 4: loss scalar (before kZQ overwrites scratch) -------------------
__global__ void kLoss(float* __restrict__ out) {
    if (threadIdx.x == 0) {
        double loss = 1.25 * (*(const double*)(out + SL_FLT)) / (double)NELEM;
        out[NELEM + N_ROWS] = (float)loss;
    }
}

// ---- pass 5: z_q gather + straight-through, fp32 out (overwrites scratch) --
__global__ void kZQ(const float* __restrict__ hs, const float* __restrict__ emb,
                    float* __restrict__ out) {
    int o = blockIdx.x * 256 + threadIdx.x;        // flat (b,c,y,x)
    int n = (o & 1023) | ((o >> 18) << 10);        // b*1024 + yx
    int c = (o >> 10) & 255;
    unsigned idx = (unsigned)out[NELEM + n] & 8191u;   // fp32 idx, exact, clamped
    float e = emb[((size_t)idx << 8) + c];
    float h = hs[o];
    // replicate ref: z_q = h + (z_q - h), elementwise fp32
    out[o] = __fadd_rn(h, __fsub_rn(e, h));
}

extern "C" void kernel_launch(void* const* d_in, const int* in_sizes, int n_in,
                              void* d_out, int out_size, void* d_ws, size_t ws_size,
                              hipStream_t stream) {
    const float* hs  = (const float*)d_in[0];   // hidden_states
    const float* emb = (const float*)d_in[1];   // emb_weights
    float* out = (float*)d_out;

    kA<<<N_ROWS / 256, 256, 0, stream>>>(hs, out);
    kGEMM<<<(N_ROWS / BM) * SPLIT, 256, 0, stream>>>(hs, emb, out);
    kPost<<<N_ROWS / 256, 256, 0, stream>>>(out);
    kLoss<<<1, 64, 0, stream>>>(out);
    kZQ<<<NELEM / 256, 256, 0, stream>>>(hs, emb, out);
}

// Round 9
// 459.322 us; speedup vs baseline: 6.0884x; 6.0884x over previous
//
#include <hip/hip_runtime.h>

// VectorQuantizer: N=16384 rows, C=256, K=8192. inputs fp32, outputs fp32
// (z_q 4194304 ++ indices 16384 ++ loss 1). r6/r7 bit-exact at ~1.1 ms,
// fp32-VALU-bound. r9: bf16-MFMA screening (R~ = 2M~-B~ via mfma C-init) +
// margin-safe flagging + exact fp32 re-rank of flagged candidates only.
// Exact path replicates ref chain bit-for-bit (same as r6) => absmax 0.
//
// margin_n = 2e-5*sqrt(A_n) + 4e-5 >= 2^-8*2.002*sqrt(A_n)*||e||max (bf16
// rounding, Cauchy-Schwarz) + 3.1e-5 (fp32 d-rounding) + chain slack; >=30%
// headroom. Flag iff R~ + margin >= rowRunningMax (any threshold <= final
// row max is safe; the argmin is always >= its own tile-group max - margin,
// so it is always flagged).
//
// Scratch in z_q float region of d_out (kZQ overwrites last); no d_ws.

#define N_ROWS 16384
#define K_CAND 8192
#define CDIM   256
#define NELEM  4194304

#define SA_FLT   0          // A[16384] fp32 (numpy-pairwise-exact)
#define SK_FLT   16384      // keys u64[16384]
#define SL_FLT   49152      // lossAcc double
#define SQC_FLT  49160      // qcount u32[512]
#define SBB_FLT  50176      // -B~ f32[8192]
#define SQ_FLT   58368      // queue u32[512*1536]
#define SFB_FLT  851968     // fbf = bf16(2*f)[16384][256] as u16
#define SEB_FLT  2949120    // ebf = bf16(e)[8192][256] as u16
#define QCAP     1536

typedef __attribute__((ext_vector_type(8))) short short8;
typedef __attribute__((ext_vector_type(4))) float f32x4;

__device__ __forceinline__ unsigned short f2bf_rne(float x) {
    unsigned u = __float_as_uint(x);
    return (unsigned short)((u + 0x7fffu + ((u >> 16) & 1u)) >> 16);
}
__device__ __forceinline__ float bf2f(unsigned short u) {
    return __uint_as_float(((unsigned)u) << 16);
}
// monotone float->u32 map (handles negatives)
__device__ __forceinline__ unsigned ordU(float f) {
    unsigned u = __float_as_uint(f);
    return u ^ (((int)u >> 31) | 0x80000000u);
}

// exact ref-chain distance + key atomicMin (bit-identical to r6 semantics)
__device__ __forceinline__ void exact_eval(const float* __restrict__ hs,
                                           const float* __restrict__ emb,
                                           const float* __restrict__ A,
                                           unsigned long long* keys,
                                           int row, int cand) {
    int b = row >> 10, yx = row & 1023;
    const float* fp = hs + ((size_t)b << 18) + yx;
    const float* ep = emb + ((size_t)cand << 8);
    float acc = 0.f;
    for (int c = 0; c < 256; ++c)
        acc = fmaf(fp[(size_t)c << 10], ep[c], acc);
    float d = __fsub_rn(A[row], __fadd_rn(acc, acc));
    unsigned long long key =
        ((unsigned long long)__float_as_uint(d) << 32) | (unsigned)cand;
    atomicMin(&keys[row], key);
}

// ---- kA: numpy-pairwise-exact A[n]; init keys + loss -----------------------
__global__ void kA(const float* __restrict__ hs, float* __restrict__ out) {
    float* A = out + SA_FLT;
    unsigned long long* keys = (unsigned long long*)(out + SK_FLT);
    int n = blockIdx.x * 256 + threadIdx.x;
    keys[n] = ~0ull;
    if (n == 0) *(double*)(out + SL_FLT) = 0.0;
    int b = n >> 10, yx = n & 1023;
    const float* base = hs + ((size_t)b << 18) + yx;
    float hsum[2];
    for (int h = 0; h < 2; ++h) {
        float r[8];
        #pragma unroll
        for (int j = 0; j < 8; ++j) {
            float x = base[(size_t)(h * 128 + j) << 10];
            r[j] = __fmul_rn(x, x);
        }
        for (int i = 8; i < 128; i += 8) {
            #pragma unroll
            for (int j = 0; j < 8; ++j) {
                float x = base[(size_t)(h * 128 + i + j) << 10];
                r[j] = __fadd_rn(r[j], __fmul_rn(x, x));
            }
        }
        hsum[h] = __fadd_rn(
            __fadd_rn(__fadd_rn(r[0], r[1]), __fadd_rn(r[2], r[3])),
            __fadd_rn(__fadd_rn(r[4], r[5]), __fadd_rn(r[6], r[7])));
    }
    A[n] = __fadd_rn(hsum[0], hsum[1]);
}

// ---- kFbf: (b,c,yx) -> bf16(2*f)[n][c] via LDS transpose -------------------
__global__ void kFbf(const float* __restrict__ hs, float* __restrict__ out) {
    unsigned short* fbf = (unsigned short*)(out + SFB_FLT);
    __shared__ float T[64][65];
    int blk = blockIdx.x;                 // 16 b x 4 cBlk x 16 yBlk = 1024
    int b = blk >> 6, cB = (blk >> 4) & 3, yB = blk & 15;
    int t = threadIdx.x;
    int yl = t & 63, ch = t >> 6;
    const float* src = hs + ((size_t)b << 18) + (((size_t)cB * 64) << 10) + yB * 64 + yl;
    #pragma unroll
    for (int i = 0; i < 16; ++i) {
        int c = ch * 16 + i;
        T[c][yl] = src[(size_t)c << 10];
    }
    __syncthreads();
    int yr = t >> 2, cs = (t & 3) * 16;
    short8 v0, v1;
    #pragma unroll
    for (int j = 0; j < 8; ++j) {
        v0[j] = (short)f2bf_rne(2.0f * T[cs + j][yr]);
        v1[j] = (short)f2bf_rne(2.0f * T[cs + 8 + j][yr]);
    }
    unsigned short* dst = fbf + (((size_t)(b * 1024 + yB * 64 + yr)) << 8) + cB * 64 + cs;
    *(short8*)dst = v0;
    *(short8*)(dst + 8) = v1;
}

// ---- kEbf: bf16(e)[cand][c] + (-B~) ---------------------------------------
__global__ void kEbf(const float* __restrict__ emb, float* __restrict__ out) {
    unsigned short* ebf = (unsigned short*)(out + SEB_FLT);
    float* bbfNeg = out + SBB_FLT;
    int cand = blockIdx.x * 256 + threadIdx.x;   // grid 32
    const float* ep = emb + ((size_t)cand << 8);
    unsigned short* dp = ebf + ((size_t)cand << 8);
    float s = 0.f;
    for (int c0 = 0; c0 < 256; c0 += 8) {
        short8 v;
        #pragma unroll
        for (int j = 0; j < 8; ++j) {
            unsigned short bb = f2bf_rne(ep[c0 + j]);
            v[j] = (short)bb;
            float eh = bf2f(bb);
            s = fmaf(eh, eh, s);
        }
        *(short8*)(dp + c0) = v;
    }
    bbfNeg[cand] = -s;
}

// ---- kMF: MFMA screening + flag queue + exact re-rank ----------------------
__global__ __launch_bounds__(256) void kMF(const float* __restrict__ hs,
                                           const float* __restrict__ emb,
                                           float* __restrict__ out) {
    const float* A = out + SA_FLT;
    unsigned long long* keys = (unsigned long long*)(out + SK_FLT);
    unsigned* qcount = (unsigned*)(out + SQC_FLT);
    const float* bbfNeg = out + SBB_FLT;
    unsigned* queue = (unsigned*)(out + SQ_FLT);
    const unsigned short* fbf = (const unsigned short*)(out + SFB_FLT);
    const unsigned short* ebf = (const unsigned short*)(out + SEB_FLT);

    __shared__ short As[128][136];        // 128 rows x 128-k half, +8 pad
    __shared__ unsigned rowMaxOrd[128];
    __shared__ float margLds[128];
    __shared__ int lqn;

    const int t = threadIdx.x, blk = blockIdx.x;
    const int row0 = (blk >> 2) * 128;
    const int candSplit = (blk & 3) * 2048;
    const int lane = t & 63, wid = t >> 6;
    const int wr = wid >> 1, wc = wid & 1;
    const int quad = lane >> 4, l15 = lane & 15;
    unsigned* qBlk = queue + (size_t)blk * QCAP;

    if (t < 128) {
        rowMaxOrd[t] = 0u;
        margLds[t] = 2.0e-5f * sqrtf(A[row0 + t]) + 4.0e-5f;
    }
    if (t == 0) lqn = 0;
    __syncthreads();

    const int rA = t >> 1, hA = t & 1;    // A staging role

    for (int cc = 0; cc < 16; ++cc) {
        const int candCC = candSplit + cc * 128;
        f32x4 acc[4][4];
        #pragma unroll
        for (int jc = 0; jc < 4; ++jc) {
            float bneg = bbfNeg[candCC + wc * 64 + jc * 16 + l15];
            #pragma unroll
            for (int m = 0; m < 4; ++m) {
                acc[m][jc][0] = bneg; acc[m][jc][1] = bneg;
                acc[m][jc][2] = bneg; acc[m][jc][3] = bneg;
            }
        }
        for (int kh = 0; kh < 2; ++kh) {
            __syncthreads();
            {   // stage A-half: row rA, 64-k segment hA
                const unsigned short* src = fbf + (((size_t)(row0 + rA)) << 8) + kh * 128 + hA * 64;
                short* dst = &As[rA][hA * 64];
                #pragma unroll
                for (int q = 0; q < 8; ++q)
                    *(short8*)(dst + 8 * q) = *(const short8*)(src + 8 * q);
            }
            __syncthreads();
            #pragma unroll
            for (int ks = 0; ks < 4; ++ks) {
                short8 af[4];
                #pragma unroll
                for (int m = 0; m < 4; ++m)
                    af[m] = *(const short8*)&As[wr * 64 + m * 16 + l15][ks * 32 + quad * 8];
                #pragma unroll
                for (int jc = 0; jc < 4; ++jc) {
                    const unsigned short* bp =
                        ebf + (((size_t)(candCC + wc * 64 + jc * 16 + l15)) << 8)
                            + kh * 128 + ks * 32 + quad * 8;
                    short8 bf = *(const short8*)bp;
                    #pragma unroll
                    for (int m = 0; m < 4; ++m)
                        acc[m][jc] = __builtin_amdgcn_mfma_f32_16x16x32_bf16(
                            af[m], bf, acc[m][jc], 0, 0, 0);
                }
            }
        }
        // group max per (m,reg): over jc in-lane, then 16-lane shuffle
        float grp[4][4];
        #pragma unroll
        for (int m = 0; m < 4; ++m)
            #pragma unroll
            for (int reg = 0; reg < 4; ++reg) {
                float v = fmaxf(fmaxf(acc[m][0][reg], acc[m][1][reg]),
                                fmaxf(acc[m][2][reg], acc[m][3][reg]));
                v = fmaxf(v, __shfl_xor(v, 1, 16));
                v = fmaxf(v, __shfl_xor(v, 2, 16));
                v = fmaxf(v, __shfl_xor(v, 4, 16));
                v = fmaxf(v, __shfl_xor(v, 8, 16));
                grp[m][reg] = v;
            }
        if (l15 == 0) {
            #pragma unroll
            for (int m = 0; m < 4; ++m)
                #pragma unroll
                for (int reg = 0; reg < 4; ++reg)
                    atomicMax(&rowMaxOrd[wr * 64 + m * 16 + quad * 4 + reg],
                              ordU(grp[m][reg]));
        }
        // flag: R~ + margin >= running row max (stale-safe)
        #pragma unroll
        for (int m = 0; m < 4; ++m)
            #pragma unroll
            for (int reg = 0; reg < 4; ++reg) {
                int rl = wr * 64 + m * 16 + quad * 4 + reg;
                unsigned th = rowMaxOrd[rl];
                unsigned og = ordU(grp[m][reg]);
                if (og > th) th = og;
                float mg = margLds[rl];
                #pragma unroll
                for (int jc = 0; jc < 4; ++jc) {
                    float v = acc[m][jc][reg];
                    if (ordU(__fadd_rn(v, mg)) >= th) {
                        int slot = atomicAdd(&lqn, 1);
                        if (slot < QCAP)
                            qBlk[slot] = ((unsigned)rl << 13)
                                       | (unsigned)(candCC + wc * 64 + jc * 16 + l15);
                    }
                }
            }
    }
    __syncthreads();
    if (t == 0) qcount[blk] = (unsigned)lqn;
    int n = lqn; if (n > QCAP) n = QCAP;
    for (int i = t; i < n; i += 256) {
        unsigned e = qBlk[i];
        exact_eval(hs, emb, A, keys, row0 + (int)(e >> 13), (int)(e & 8191u));
    }
}

// ---- kFallback: exact full scan for overflowed blocks (normally no-op) -----
__global__ void kFallback(const float* __restrict__ hs, const float* __restrict__ emb,
                          float* __restrict__ out) {
    unsigned* qcount = (unsigned*)(out + SQC_FLT);
    if (qcount[blockIdx.x] <= QCAP) return;
    const float* A = out + SA_FLT;
    unsigned long long* keys = (unsigned long long*)(out + SK_FLT);
    int row0 = (int)(blockIdx.x >> 2) * 128, cb = (int)(blockIdx.x & 3) * 2048;
    for (int p = threadIdx.x; p < 128 * 2048; p += 256)
        exact_eval(hs, emb, A, keys, row0 + (p >> 11), cb + (p & 2047));
}

// ---- kPost / kLoss / kZQ (unchanged from r6) -------------------------------
__global__ void kPost(float* __restrict__ out) {
    const unsigned long long* keys = (const unsigned long long*)(out + SK_FLT);
    double* lossAcc = (double*)(out + SL_FLT);
    __shared__ double sd[256];
    int n = blockIdx.x * 256 + threadIdx.x;
    unsigned long long key = keys[n];
    unsigned idx = (unsigned)(key & 0xffffffffu) & 8191u;
    float d = __uint_as_float((unsigned)(key >> 32));
    out[NELEM + n] = (float)idx;
    sd[threadIdx.x] = (double)d;
    __syncthreads();
    for (int s = 128; s > 0; s >>= 1) {
        if (threadIdx.x < s) sd[threadIdx.x] += sd[threadIdx.x + s];
        __syncthreads();
    }
    if (threadIdx.x == 0) atomicAdd(lossAcc, sd[0]);
}

__global__ void kLoss(float* __restrict__ out) {
    if (threadIdx.x == 0) {
        double loss = 1.25 * (*(const double*)(out + SL_FLT)) / (double)NELEM;
        out[NELEM + N_ROWS] = (float)loss;
    }
}

__global__ void kZQ(const float* __restrict__ hs, const float* __restrict__ emb,
                    float* __restrict__ out) {
    int o = blockIdx.x * 256 + threadIdx.x;
    int n = (o & 1023) | ((o >> 18) << 10);
    int c = (o >> 10) & 255;
    unsigned idx = (unsigned)out[NELEM + n] & 8191u;
    float e = emb[((size_t)idx << 8) + c];
    float h = hs[o];
    out[o] = __fadd_rn(h, __fsub_rn(e, h));
}

extern "C" void kernel_launch(void* const* d_in, const int* in_sizes, int n_in,
                              void* d_out, int out_size, void* d_ws, size_t ws_size,
                              hipStream_t stream) {
    const float* hs  = (const float*)d_in[0];
    const float* emb = (const float*)d_in[1];
    float* out = (float*)d_out;

    kA<<<N_ROWS / 256, 256, 0, stream>>>(hs, out);
    kFbf<<<1024, 256, 0, stream>>>(hs, out);
    kEbf<<<K_CAND / 256, 256, 0, stream>>>(emb, out);
    kMF<<<512, 256, 0, stream>>>(hs, emb, out);
    kFallback<<<512, 256, 0, stream>>>(hs, emb, out);
    kPost<<<N_ROWS / 256, 256, 0, stream>>>(out);
    kLoss<<<1, 64, 0, stream>>>(out);
    kZQ<<<NELEM / 256, 256, 0, stream>>>(hs, emb, out);
}

// Round 10
// 439.993 us; speedup vs baseline: 6.3559x; 1.0439x over previous
//
#include <hip/hip_runtime.h>

// VectorQuantizer: N=16384 rows, C=256, K=8192. inputs fp32, outputs fp32
// (z_q 4194304 ++ indices 16384 ++ loss 1). r9 (MFMA screen + exact re-rank)
// passed bit-exact at 459 us; kMF was 319 us with MfmaUtil 8.8% (29 us of
// real MFMA) -- overhead = per-cc re-staging + 64 barriers + LDS conflicts.
// r10: stage A-tile ONCE per block (full K, 66 KB LDS), barrier-free cc loop,
// B-frags direct from global (L1/L2), ballot-gated flag logic. Exact path
// (sequential-fmaf chain, u64 key tie-break) byte-identical to r9.
//
// margin_n = 2e-5*sqrt(A_n) + 4e-5; flag iff R~ + margin >= rowRunningMax
// (monotone LDS atomicMax; stale threshold only over-flags => safe).
//
// Scratch in z_q float region of d_out (kZQ overwrites last); no d_ws.

#define N_ROWS 16384
#define K_CAND 8192
#define CDIM   256
#define NELEM  4194304

#define SA_FLT   0          // A[16384] fp32 (numpy-pairwise-exact)
#define SK_FLT   16384      // keys u64[16384]
#define SL_FLT   49152      // lossAcc double
#define SQC_FLT  49160      // qcount u32[512]
#define SBB_FLT  50176      // -B~ f32[8192]
#define SQ_FLT   58368      // queue u32[512*1536]
#define SFB_FLT  851968     // fbf = bf16(2*f)[16384][256] as u16
#define SEB_FLT  2949120    // ebf = bf16(e)[8192][256] as u16
#define QCAP     1536

typedef __attribute__((ext_vector_type(8))) short short8;
typedef __attribute__((ext_vector_type(4))) float f32x4;

__device__ __forceinline__ unsigned short f2bf_rne(float x) {
    unsigned u = __float_as_uint(x);
    return (unsigned short)((u + 0x7fffu + ((u >> 16) & 1u)) >> 16);
}
__device__ __forceinline__ float bf2f(unsigned short u) {
    return __uint_as_float(((unsigned)u) << 16);
}
// monotone float->u32 map (handles negatives)
__device__ __forceinline__ unsigned ordU(float f) {
    unsigned u = __float_as_uint(f);
    return u ^ (((int)u >> 31) | 0x80000000u);
}

// exact ref-chain distance + key atomicMin (bit-identical to r6/r9 semantics)
__device__ __forceinline__ void exact_eval(const float* __restrict__ hs,
                                           const float* __restrict__ emb,
                                           const float* __restrict__ A,
                                           unsigned long long* keys,
                                           int row, int cand) {
    int b = row >> 10, yx = row & 1023;
    const float* fp = hs + ((size_t)b << 18) + yx;
    const float* ep = emb + ((size_t)cand << 8);
    float acc = 0.f;
    for (int c = 0; c < 256; ++c)
        acc = fmaf(fp[(size_t)c << 10], ep[c], acc);
    float d = __fsub_rn(A[row], __fadd_rn(acc, acc));
    unsigned long long key =
        ((unsigned long long)__float_as_uint(d) << 32) | (unsigned)cand;
    atomicMin(&keys[row], key);
}

// ---- kA: numpy-pairwise-exact A[n]; init keys + loss -----------------------
__global__ void kA(const float* __restrict__ hs, float* __restrict__ out) {
    float* A = out + SA_FLT;
    unsigned long long* keys = (unsigned long long*)(out + SK_FLT);
    int n = blockIdx.x * 256 + threadIdx.x;
    keys[n] = ~0ull;
    if (n == 0) *(double*)(out + SL_FLT) = 0.0;
    int b = n >> 10, yx = n & 1023;
    const float* base = hs + ((size_t)b << 18) + yx;
    float hsum[2];
    for (int h = 0; h < 2; ++h) {
        float r[8];
        #pragma unroll
        for (int j = 0; j < 8; ++j) {
            float x = base[(size_t)(h * 128 + j) << 10];
            r[j] = __fmul_rn(x, x);
        }
        for (int i = 8; i < 128; i += 8) {
            #pragma unroll
            for (int j = 0; j < 8; ++j) {
                float x = base[(size_t)(h * 128 + i + j) << 10];
                r[j] = __fadd_rn(r[j], __fmul_rn(x, x));
            }
        }
        hsum[h] = __fadd_rn(
            __fadd_rn(__fadd_rn(r[0], r[1]), __fadd_rn(r[2], r[3])),
            __fadd_rn(__fadd_rn(r[4], r[5]), __fadd_rn(r[6], r[7])));
    }
    A[n] = __fadd_rn(hsum[0], hsum[1]);
}

// ---- kFbf: (b,c,yx) -> bf16(2*f)[n][c] via LDS transpose -------------------
__global__ void kFbf(const float* __restrict__ hs, float* __restrict__ out) {
    unsigned short* fbf = (unsigned short*)(out + SFB_FLT);
    __shared__ float T[64][65];
    int blk = blockIdx.x;                 // 16 b x 4 cBlk x 16 yBlk = 1024
    int b = blk >> 6, cB = (blk >> 4) & 3, yB = blk & 15;
    int t = threadIdx.x;
    int yl = t & 63, ch = t >> 6;
    const float* src = hs + ((size_t)b << 18) + (((size_t)cB * 64) << 10) + yB * 64 + yl;
    #pragma unroll
    for (int i = 0; i < 16; ++i) {
        int c = ch * 16 + i;
        T[c][yl] = src[(size_t)c << 10];
    }
    __syncthreads();
    int yr = t >> 2, cs = (t & 3) * 16;
    short8 v0, v1;
    #pragma unroll
    for (int j = 0; j < 8; ++j) {
        v0[j] = (short)f2bf_rne(2.0f * T[cs + j][yr]);
        v1[j] = (short)f2bf_rne(2.0f * T[cs + 8 + j][yr]);
    }
    unsigned short* dst = fbf + (((size_t)(b * 1024 + yB * 64 + yr)) << 8) + cB * 64 + cs;
    *(short8*)dst = v0;
    *(short8*)(dst + 8) = v1;
}

// ---- kEbf: bf16(e)[cand][c] + (-B~) ---------------------------------------
__global__ void kEbf(const float* __restrict__ emb, float* __restrict__ out) {
    unsigned short* ebf = (unsigned short*)(out + SEB_FLT);
    float* bbfNeg = out + SBB_FLT;
    int cand = blockIdx.x * 256 + threadIdx.x;   // grid 32
    const float* ep = emb + ((size_t)cand << 8);
    unsigned short* dp = ebf + ((size_t)cand << 8);
    float s = 0.f;
    for (int c0 = 0; c0 < 256; c0 += 8) {
        short8 v;
        #pragma unroll
        for (int j = 0; j < 8; ++j) {
            unsigned short bb = f2bf_rne(ep[c0 + j]);
            v[j] = (short)bb;
            float eh = bf2f(bb);
            s = fmaf(eh, eh, s);
        }
        *(short8*)(dp + c0) = v;
    }
    bbfNeg[cand] = -s;
}

// ---- kMF: MFMA screening (barrier-free K-loop) + flags + exact re-rank -----
__global__ __launch_bounds__(256, 2) void kMF(const float* __restrict__ hs,
                                              const float* __restrict__ emb,
                                              float* __restrict__ out) {
    const float* A = out + SA_FLT;
    unsigned long long* keys = (unsigned long long*)(out + SK_FLT);
    unsigned* qcount = (unsigned*)(out + SQC_FLT);
    const float* bbfNeg = out + SBB_FLT;
    unsigned* queue = (unsigned*)(out + SQ_FLT);
    const unsigned short* fbf = (const unsigned short*)(out + SFB_FLT);
    const unsigned short* ebf = (const unsigned short*)(out + SEB_FLT);

    __shared__ short As[128][264];        // full 256-k A-tile, stride 132 dw
    __shared__ unsigned rowMaxOrd[128];
    __shared__ float margLds[128];
    __shared__ int lqn;

    const int t = threadIdx.x, blk = blockIdx.x;
    const int row0 = (blk >> 2) * 128;
    const int candSplit = (blk & 3) * 2048;
    const int lane = t & 63, wid = t >> 6;
    const int wr = wid >> 1, wc = wid & 1;
    const int quad = lane >> 4, l15 = lane & 15;
    unsigned* qBlk = queue + (size_t)blk * QCAP;

    if (t < 128) {
        rowMaxOrd[t] = 0u;
        margLds[t] = 2.0e-5f * sqrtf(A[row0 + t]) + 4.0e-5f;
    }
    if (t == 0) lqn = 0;

    // stage full A-tile ONCE: coalesced 16-B global loads, linear->2D LDS
    {
        const unsigned short* src = fbf + ((size_t)row0 << 8);
        #pragma unroll
        for (int i = 0; i < 16; ++i) {
            int idx = (i * 256 + t) * 8;          // linear short offset
            short8 v = *(const short8*)(src + idx);
            *(short8*)&As[idx >> 8][idx & 255] = v;
        }
    }
    __syncthreads();     // the ONLY barrier before the tail

    for (int cc = 0; cc < 16; ++cc) {
        const int candCC = candSplit + cc * 128;
        const int candW = candCC + wc * 64;
        f32x4 acc[4][4];
        #pragma unroll
        for (int jc = 0; jc < 4; ++jc) {
            float bneg = bbfNeg[candW + jc * 16 + l15];
            #pragma unroll
            for (int m = 0; m < 4; ++m)
                acc[m][jc] = (f32x4){bneg, bneg, bneg, bneg};
        }
        #pragma unroll
        for (int ks = 0; ks < 8; ++ks) {
            short8 bf[4];
            #pragma unroll
            for (int jc = 0; jc < 4; ++jc)
                bf[jc] = *(const short8*)(ebf + (((size_t)(candW + jc * 16 + l15)) << 8)
                                              + ks * 32 + quad * 8);
            #pragma unroll
            for (int m = 0; m < 4; ++m) {
                short8 af = *(const short8*)&As[wr * 64 + m * 16 + l15][ks * 32 + quad * 8];
                #pragma unroll
                for (int jc = 0; jc < 4; ++jc)
                    acc[m][jc] = __builtin_amdgcn_mfma_f32_16x16x32_bf16(
                        af, bf[jc], acc[m][jc], 0, 0, 0);
            }
        }
        // flag: per-(m,reg) early-out; ballot consensus so the 16-lane
        // shuffle-max never runs with inactive lanes (garbage-max hazard)
        #pragma unroll
        for (int m = 0; m < 4; ++m)
            #pragma unroll
            for (int reg = 0; reg < 4; ++reg) {
                int rl = wr * 64 + m * 16 + quad * 4 + reg;
                float vmax = fmaxf(fmaxf(acc[m][0][reg], acc[m][1][reg]),
                                   fmaxf(acc[m][2][reg], acc[m][3][reg]));
                unsigned th = rowMaxOrd[rl];
                float mg = margLds[rl];
                bool hot = ordU(__fadd_rn(vmax, mg)) >= th;
                unsigned long long bal = __ballot(hot);
                if (((bal >> (quad * 16)) & 0xFFFFull) == 0ull) continue;
                float g = vmax;                       // all 16 lanes active
                g = fmaxf(g, __shfl_xor(g, 1, 16));
                g = fmaxf(g, __shfl_xor(g, 2, 16));
                g = fmaxf(g, __shfl_xor(g, 4, 16));
                g = fmaxf(g, __shfl_xor(g, 8, 16));
                unsigned og = ordU(g);
                if (og > th) { atomicMax(&rowMaxOrd[rl], og); th = og; }
                #pragma unroll
                for (int jc = 0; jc < 4; ++jc) {
                    float x = acc[m][jc][reg];
                    if (ordU(__fadd_rn(x, mg)) >= th) {
                        int slot = atomicAdd(&lqn, 1);
                        if (slot < QCAP)
                            qBlk[slot] = ((unsigned)rl << 13)
                                       | (unsigned)(candW + jc * 16 + l15);
                    }
                }
            }
    }
    __syncthreads();
    if (t == 0) qcount[blk] = (unsigned)lqn;
    int n = lqn; if (n > QCAP) n = QCAP;
    for (int i = t; i < n; i += 256) {
        unsigned e = qBlk[i];
        exact_eval(hs, emb, A, keys, row0 + (int)(e >> 13), (int)(e & 8191u));
    }
}

// ---- kFallback: exact full scan for overflowed blocks (normally no-op) -----
__global__ void kFallback(const float* __restrict__ hs, const float* __restrict__ emb,
                          float* __restrict__ out) {
    unsigned* qcount = (unsigned*)(out + SQC_FLT);
    if (qcount[blockIdx.x] <= QCAP) return;
    const float* A = out + SA_FLT;
    unsigned long long* keys = (unsigned long long*)(out + SK_FLT);
    int row0 = (int)(blockIdx.x >> 2) * 128, cb = (int)(blockIdx.x & 3) * 2048;
    for (int p = threadIdx.x; p < 128 * 2048; p += 256)
        exact_eval(hs, emb, A, keys, row0 + (p >> 11), cb + (p & 2047));
}

// ---- kPost / kLoss / kZQ (unchanged) ---------------------------------------
__global__ void kPost(float* __restrict__ out) {
    const unsigned long long* keys = (const unsigned long long*)(out + SK_FLT);
    double* lossAcc = (double*)(out + SL_FLT);
    __shared__ double sd[256];
    int n = blockIdx.x * 256 + threadIdx.x;
    unsigned long long key = keys[n];
    unsigned idx = (unsigned)(key & 0xffffffffu) & 8191u;
    float d = __uint_as_float((unsigned)(key >> 32));
    out[NELEM + n] = (float)idx;
    sd[threadIdx.x] = (double)d;
    __syncthreads();
    for (int s = 128; s > 0; s >>= 1) {
        if (threadIdx.x < s) sd[threadIdx.x] += sd[threadIdx.x + s];
        __syncthreads();
    }
    if (threadIdx.x == 0) atomicAdd(lossAcc, sd[0]);
}

__global__ void kLoss(float* __restrict__ out) {
    if (threadIdx.x == 0) {
        double loss = 1.25 * (*(const double*)(out + SL_FLT)) / (double)NELEM;
        out[NELEM + N_ROWS] = (float)loss;
    }
}

__global__ void kZQ(const float* __restrict__ hs, const float* __restrict__ emb,
                    float* __restrict__ out) {
    int o = blockIdx.x * 256 + threadIdx.x;
    int n = (o & 1023) | ((o >> 18) << 10);
    int c = (o >> 10) & 255;
    unsigned idx = (unsigned)out[NELEM + n] & 8191u;
    float e = emb[((size_t)idx << 8) + c];
    float h = hs[o];
    out[o] = __fadd_rn(h, __fsub_rn(e, h));
}

extern "C" void kernel_launch(void* const* d_in, const int* in_sizes, int n_in,
                              void* d_out, int out_size, void* d_ws, size_t ws_size,
                              hipStream_t stream) {
    const float* hs  = (const float*)d_in[0];
    const float* emb = (const float*)d_in[1];
    float* out = (float*)d_out;

    kA<<<N_ROWS / 256, 256, 0, stream>>>(hs, out);
    kFbf<<<1024, 256, 0, stream>>>(hs, out);
    kEbf<<<K_CAND / 256, 256, 0, stream>>>(emb, out);
    kMF<<<512, 256, 0, stream>>>(hs, emb, out);
    kFallback<<<512, 256, 0, stream>>>(hs, emb, out);
    kPost<<<N_ROWS / 256, 256, 0, stream>>>(out);
    kLoss<<<1, 64, 0, stream>>>(out);
    kZQ<<<NELEM / 256, 256, 0, stream>>>(hs, emb, out);
}